// Round 3
// baseline (1812.141 us; speedup 1.0000x reference)
//
#include <hip/hip_runtime.h>
#include <stdint.h>

#define Bb   16
#define INn  8192
#define Cc   64
#define Aa   512
#define Nn   512
#define OUTo 1024
#define Tt   32

// ---------------------------------------------------------------------------
// Spike schedule per (b, i) as a 32-bit mask (bit t = spike at cycle t).
// ---------------------------------------------------------------------------
__global__ void spike_kernel(const float* __restrict__ x,
                             uint32_t* __restrict__ spk) {
    int idx = blockIdx.x * 256 + threadIdx.x;
    if (idx >= Bb * INn) return;
    float xv = x[idx];
    float nf = rintf(xv * 32.0f);
    int nspk = (int)nf;
    uint32_t m;
    if (nspk >= 32) {
        m = 0xFFFFFFFFu;
    } else if (nspk <= 0) {
        m = 0u;
    } else {
        float spacing = 32.0f / nf;
        m = 0u;
        #pragma unroll
        for (int t = 0; t < 32; ++t) {
            float ct = (float)t;
            bool fire = (floorf(ct / spacing) < nf) &&
                        (floorf(fmodf(ct, spacing)) == 0.0f);
            if (fire) m |= (1u << t);
        }
    }
    spk[idx] = m;
}

// ---------------------------------------------------------------------------
// One-time W transpose into a-major packed layout:
//   Wt4[(c*128 + ab)*512 + n] = float4{ W[c][n][4ab+0..3] }
// so cycle_kernel W loads are lane-contiguous (lane = n).
// grid (64, 8, 8): (c, n-tile of 64, a-tile of 64); 256 threads.
// ---------------------------------------------------------------------------
__global__ __launch_bounds__(256) void transpose_kernel(
        const float* __restrict__ W, float4* __restrict__ Wt4) {
    __shared__ float lds[64 * 65];
    const int c  = blockIdx.x;
    const int nt = blockIdx.y;
    const int at = blockIdx.z;
    const int tx = threadIdx.x & 63;
    const int ty = threadIdx.x >> 6;

    const float* src = W + (size_t)c * Nn * Aa;
    for (int r = ty; r < 64; r += 4) {          // r = n within tile, tx = a
        lds[r * 65 + tx] = src[(size_t)(nt * 64 + r) * Aa + at * 64 + tx];
    }
    __syncthreads();
    #pragma unroll
    for (int i = 0; i < 4; ++i) {
        int ab = i * 4 + ty;                    // a-block within tile (0..15)
        float4 w4;
        w4.x = lds[tx * 65 + ab * 4 + 0];       // tx = n within tile
        w4.y = lds[tx * 65 + ab * 4 + 1];
        w4.z = lds[tx * 65 + ab * 4 + 2];
        w4.w = lds[tx * 65 + ab * 4 + 3];
        int abg = at * 16 + ab;                 // global a-block (0..127)
        Wt4[(size_t)(c * 128 + abg) * Nn + nt * 64 + tx] = w4;
    }
}

// ---------------------------------------------------------------------------
// Per-cycle signal gather: sig[c][a][b] = 0.0f / 1.0f  (layout [c*512+a][16]).
// ---------------------------------------------------------------------------
__global__ void gather_kernel(const int* __restrict__ src_core,
                              const int* __restrict__ src_index,
                              const uint32_t* __restrict__ spk,
                              const uint32_t* __restrict__ buf,
                              float* __restrict__ sig, int t) {
    int idx = blockIdx.x * 256 + threadIdx.x;    // over C*A*16
    int b  = idx & 15;
    int ca = idx >> 4;
    int sc = src_core[ca];
    int si = src_index[ca];
    float v;
    if (sc < 0) {
        v = (float)((spk[b * INn + si] >> t) & 1u);
    } else {
        v = (t > 0) ? (float)((buf[(sc * Bb + b) * Nn + si] >> (t - 1)) & 1u)
                    : 0.0f;
    }
    sig[ca * 16 + b] = v;
}

// ---------------------------------------------------------------------------
// Cycle kernel, transposed-W path. Grid (64, 8) x 256 threads (4 waves).
// Wave wv (0..3) owns batch-quad sb=4*wv; lane owns n = blockIdx.y*64+lane.
// W float4 loads are lane-contiguous; 8-deep software pipeline. sig reads
// are wave-uniform -> scalar loads. Accumulation over a is strictly
// ascending per (n,b) accumulator -> bit-identical to validated rounds.
// ---------------------------------------------------------------------------
#define FMA4A(w4, sa)                                              \
    acc0 += (w4).x * (sa)[0];   acc1 += (w4).x * (sa)[1];          \
    acc2 += (w4).x * (sa)[2];   acc3 += (w4).x * (sa)[3];          \
    acc0 += (w4).y * (sa)[16];  acc1 += (w4).y * (sa)[17];         \
    acc2 += (w4).y * (sa)[18];  acc3 += (w4).y * (sa)[19];         \
    acc0 += (w4).z * (sa)[32];  acc1 += (w4).z * (sa)[33];         \
    acc2 += (w4).z * (sa)[34];  acc3 += (w4).z * (sa)[35];         \
    acc0 += (w4).w * (sa)[48];  acc1 += (w4).w * (sa)[49];         \
    acc2 += (w4).w * (sa)[50];  acc3 += (w4).w * (sa)[51];

__global__ __launch_bounds__(256) void cycle_kernel(
        const float4* __restrict__ Wt4,
        const float* __restrict__ thr,
        const float* __restrict__ sig,
        uint32_t* __restrict__ buf,
        float* __restrict__ memb,
        int t) {
    const int c    = blockIdx.x;
    const int lane = threadIdx.x & 63;
    const int wv   = __builtin_amdgcn_readfirstlane(threadIdx.x >> 6);
    const int sb   = wv * 4;
    const int n    = blockIdx.y * 64 + lane;

    const float4* __restrict__ wp  = Wt4 + (size_t)(c * 128) * Nn + n;
    const float*  __restrict__ sgp = sig + (size_t)c * Aa * Bb + sb;

    float acc0 = 0.f, acc1 = 0.f, acc2 = 0.f, acc3 = 0.f;

    float4 wbuf[8];
    #pragma unroll
    for (int k = 0; k < 8; ++k) wbuf[k] = wp[(size_t)k * Nn];

    for (int ab0 = 0; ab0 < 120; ab0 += 8) {
        #pragma unroll
        for (int k = 0; k < 8; ++k) {
            float4 w4 = wbuf[k];
            wbuf[k] = wp[(size_t)(ab0 + 8 + k) * Nn];   // prefetch
            const float* sa = sgp + (size_t)(ab0 + k) * 64;
            FMA4A(w4, sa)
        }
    }
    #pragma unroll
    for (int k = 0; k < 8; ++k) {                        // tail, no prefetch
        float4 w4 = wbuf[k];
        const float* sa = sgp + (size_t)(120 + k) * 64;
        FMA4A(w4, sa)
    }

    const float th = thr[c];
    float accs[4] = {acc0, acc1, acc2, acc3};
    #pragma unroll
    for (int j = 0; j < 4; ++j) {
        size_t off = ((size_t)c * Bb + (sb + j)) * Nn + n;
        float m = memb[off] + accs[j];     // single add, like reference
        uint32_t wd = buf[off];
        if (th < m) {                       // strict <, like reference
            m -= th;
            wd |= (1u << t);
        }
        memb[off] = m;
        buf[off] = wd;
    }
}

// ---------------------------------------------------------------------------
// Fallback cycle kernel (round-2, known-correct) if ws can't hold Wt4.
// ---------------------------------------------------------------------------
__global__ __launch_bounds__(128) void cycle_kernel_fb(
        const float* __restrict__ W,
        const float* __restrict__ thr,
        const float* __restrict__ sig,
        uint32_t* __restrict__ buf,
        float* __restrict__ memb,
        int t) {
    const int c  = blockIdx.x;
    const int bh = __builtin_amdgcn_readfirstlane(threadIdx.x >> 6);
    const int n  = blockIdx.y * 64 + (threadIdx.x & 63);

    const float* __restrict__ wrow = W + (size_t)(c * Nn + n) * Aa;
    const float* __restrict__ sgc  = sig + c * Aa * 16 + bh * 8;

    float acc[8];
    #pragma unroll
    for (int j = 0; j < 8; ++j) acc[j] = 0.0f;

    for (int a0 = 0; a0 < Aa; a0 += 4) {
        float4 w4 = *(const float4*)(wrow + a0);
        #pragma unroll
        for (int k = 0; k < 4; ++k) {
            float w = (k == 0) ? w4.x : (k == 1) ? w4.y : (k == 2) ? w4.z : w4.w;
            const float* sa = sgc + (size_t)(a0 + k) * 16;
            #pragma unroll
            for (int j = 0; j < 8; ++j) acc[j] += w * sa[j];
        }
    }

    const float th = thr[c];
    #pragma unroll
    for (int j = 0; j < 8; ++j) {
        int b = bh * 8 + j;
        size_t off = (size_t)(c * Bb + b) * Nn + n;
        float m = memb[off] + acc[j];
        uint32_t wd = buf[off];
        if (th < m) { m -= th; wd |= (1u << t); }
        memb[off] = m;
        buf[off] = wd;
    }
}

// ---------------------------------------------------------------------------
// out[b, o] = popcount(buf[oc[o], b, oi[o]]).
// ---------------------------------------------------------------------------
__global__ void out_kernel(const uint32_t* __restrict__ buf,
                           const int* __restrict__ oc,
                           const int* __restrict__ oi,
                           float* __restrict__ out) {
    int idx = blockIdx.x * 256 + threadIdx.x;
    if (idx >= Bb * OUTo) return;
    int b = idx / OUTo;
    int o = idx - b * OUTo;
    uint32_t wd = buf[(oc[o] * Bb + b) * Nn + oi[o]];
    out[idx] = (float)__popc(wd);
}

extern "C" void kernel_launch(void* const* d_in, const int* in_sizes, int n_in,
                              void* d_out, int out_size, void* d_ws,
                              size_t ws_size, hipStream_t stream) {
    const float* x         = (const float*)d_in[0];
    const float* W         = (const float*)d_in[1];
    const float* thr       = (const float*)d_in[2];
    const int*   src_core  = (const int*)d_in[3];
    const int*   src_index = (const int*)d_in[4];
    const int*   osc       = (const int*)d_in[5];
    const int*   osi       = (const int*)d_in[6];
    float* out = (float*)d_out;

    // ws layout: spk | buf | memb | sig | Wt4
    char* p = (char*)d_ws;
    uint32_t* spk  = (uint32_t*)p;   p += (size_t)Bb * INn * 4;
    uint32_t* buf  = (uint32_t*)p;   p += (size_t)Cc * Bb * Nn * 4;
    float*    memb = (float*)p;      p += (size_t)Cc * Bb * Nn * 4;
    float*    sig  = (float*)p;      p += (size_t)Cc * Aa * Bb * 4;
    // align Wt4 to 16 B
    p = (char*)(((uintptr_t)p + 15) & ~(uintptr_t)15);
    float4*   Wt4  = (float4*)p;     p += (size_t)Cc * Aa * Nn * 4;
    const bool use_t = ((size_t)(p - (char*)d_ws) <= ws_size);

    hipMemsetAsync(buf, 0, (size_t)Cc * Bb * Nn * 4 * 2, stream);

    spike_kernel<<<dim3((Bb * INn) / 256), 256, 0, stream>>>(x, spk);

    if (use_t) {
        transpose_kernel<<<dim3(Cc, 8, 8), 256, 0, stream>>>(W, Wt4);
        for (int t = 0; t < Tt; ++t) {
            gather_kernel<<<dim3((Cc * Aa * Bb) / 256), 256, 0, stream>>>(
                src_core, src_index, spk, buf, sig, t);
            cycle_kernel<<<dim3(Cc, 8), 256, 0, stream>>>(
                Wt4, thr, sig, buf, memb, t);
        }
    } else {
        for (int t = 0; t < Tt; ++t) {
            gather_kernel<<<dim3((Cc * Aa * Bb) / 256), 256, 0, stream>>>(
                src_core, src_index, spk, buf, sig, t);
            cycle_kernel_fb<<<dim3(Cc, 8), 128, 0, stream>>>(
                W, thr, sig, buf, memb, t);
        }
    }

    out_kernel<<<dim3((Bb * OUTo + 255) / 256), 256, 0, stream>>>(
        buf, osc, osi, out);
}

// Round 4
// 1592.601 us; speedup vs baseline: 1.1379x; 1.1379x over previous
//
#include <hip/hip_runtime.h>
#include <stdint.h>

#define Bb   16
#define INn  8192
#define Cc   64
#define Aa   512
#define Nn   512
#define OUTo 1024
#define Tt   32

// ---------------------------------------------------------------------------
// Spike schedule per (b, i) as a 32-bit mask (bit t = spike at cycle t).
// ---------------------------------------------------------------------------
__global__ void spike_kernel(const float* __restrict__ x,
                             uint32_t* __restrict__ spk) {
    int idx = blockIdx.x * 256 + threadIdx.x;
    if (idx >= Bb * INn) return;
    float xv = x[idx];
    float nf = rintf(xv * 32.0f);
    int nspk = (int)nf;
    uint32_t m;
    if (nspk >= 32) {
        m = 0xFFFFFFFFu;
    } else if (nspk <= 0) {
        m = 0u;
    } else {
        float spacing = 32.0f / nf;
        m = 0u;
        #pragma unroll
        for (int t = 0; t < 32; ++t) {
            float ct = (float)t;
            bool fire = (floorf(ct / spacing) < nf) &&
                        (floorf(fmodf(ct, spacing)) == 0.0f);
            if (fire) m |= (1u << t);
        }
    }
    spk[idx] = m;
}

// ---------------------------------------------------------------------------
// One-time W transpose into block-contiguous a-major layout:
//   Wt[((c*8 + y)*128 + ab)*64 + ln] = float4{ W[c][y*64+ln][4ab .. 4ab+3] }
// Each cycle-kernel block (c,y,*) then streams a CONTIGUOUS 128 KB region.
// grid (64, 8, 8): (c, n-tile, a-tile); 256 threads.
// ---------------------------------------------------------------------------
__global__ __launch_bounds__(256) void transpose_kernel(
        const float* __restrict__ W, float4* __restrict__ Wt) {
    __shared__ float lds[64 * 65];
    const int c  = blockIdx.x;
    const int nt = blockIdx.y;
    const int at = blockIdx.z;
    const int tx = threadIdx.x & 63;
    const int ty = threadIdx.x >> 6;

    const float* src = W + (size_t)c * Nn * Aa;
    for (int r = ty; r < 64; r += 4) {          // r = n within tile, tx = a
        lds[r * 65 + tx] = src[(size_t)(nt * 64 + r) * Aa + at * 64 + tx];
    }
    __syncthreads();
    #pragma unroll
    for (int i = 0; i < 4; ++i) {
        int ab = i * 4 + ty;                    // a-block within tile (0..15)
        float4 w4;
        w4.x = lds[tx * 65 + ab * 4 + 0];       // tx = n within tile
        w4.y = lds[tx * 65 + ab * 4 + 1];
        w4.z = lds[tx * 65 + ab * 4 + 2];
        w4.w = lds[tx * 65 + ab * 4 + 3];
        size_t dst = ((size_t)(c * 8 + nt) * 128 + (at * 16 + ab)) * 64 + tx;
        Wt[dst] = w4;
    }
}

// ---------------------------------------------------------------------------
// Per-cycle signal gather as bit-planes:
//   planes[(b*64 + c)*16 + aw] bit j = signal(c, a = aw*32 + j, b)
// 16K threads, one word (32 signals) each.
// ---------------------------------------------------------------------------
__global__ void gatherbits_kernel(const int* __restrict__ src_core,
                                  const int* __restrict__ src_index,
                                  const uint32_t* __restrict__ spk,
                                  const uint32_t* __restrict__ buf,
                                  uint32_t* __restrict__ planes, int t) {
    int idx = blockIdx.x * 256 + threadIdx.x;    // (b*64 + c)*16 + aw
    int aw = idx & 15;
    int bc = idx >> 4;
    int c  = bc & 63;
    int b  = bc >> 6;
    int abase = c * Aa + aw * 32;
    uint32_t word = 0;
    #pragma unroll 4
    for (int j = 0; j < 32; ++j) {
        int sc = src_core[abase + j];
        int si = src_index[abase + j];
        uint32_t bit;
        if (sc < 0) {
            bit = (spk[b * INn + si] >> t) & 1u;
        } else {
            bit = (t > 0) ? ((buf[(sc * Bb + b) * Nn + si] >> (t - 1)) & 1u)
                          : 0u;
        }
        word |= bit << j;
    }
    planes[idx] = word;
}

// ---------------------------------------------------------------------------
// Cycle kernel. Grid (64, 8, 2) x 256 threads (4 waves), all co-resident
// (4096 waves = 4/SIMD). Wave wv of block (c,y,z) owns b-pair b0 = z*8+wv*2;
// lane owns n = y*64 + ln. W is streamed from the block-contiguous Wt in
// double-buffered batches of 8 float4 (16 loads in flight). Signal bits come
// from two wave-uniform dwords per batch; the 0/1 select is wave-uniform
// (SALU) feeding v_fmac with an SGPR multiplicand -> 1 VALU op per product.
// fmaf(1,w,acc)=acc+w and fmaf(0,w,acc)=acc exactly; ascending-a order per
// accumulator -> bit-identical to the validated rounds.
// ---------------------------------------------------------------------------
__device__ __forceinline__ void load_batch(float4 (&wb)[8],
        const float4* __restrict__ wp, int ab0) {
    #pragma unroll
    for (int k = 0; k < 8; ++k) wb[k] = wp[(ab0 + k) * 64];
}

__device__ __forceinline__ void compute_batch(const float4 (&wb)[8],
        uint32_t u0, uint32_t u1, float& acc0, float& acc1) {
    #pragma unroll
    for (int k = 0; k < 8; ++k) {
        const float w[4] = {wb[k].x, wb[k].y, wb[k].z, wb[k].w};
        #pragma unroll
        for (int q = 0; q < 4; ++q) {
            const int bitp = 4 * k + q;          // compile-time after unroll
            float s0 = ((u0 >> bitp) & 1u) ? 1.0f : 0.0f;  // wave-uniform
            float s1 = ((u1 >> bitp) & 1u) ? 1.0f : 0.0f;
            acc0 = fmaf(s0, w[q], acc0);
            acc1 = fmaf(s1, w[q], acc1);
        }
    }
}

__global__ __launch_bounds__(256, 4) void cycle_kernel(
        const float4* __restrict__ Wt,
        const float* __restrict__ thr,
        const uint32_t* __restrict__ planes,
        uint32_t* __restrict__ buf,
        float* __restrict__ memb,
        int t) {
    const int c  = blockIdx.x;
    const int y  = blockIdx.y;
    const int z  = blockIdx.z;
    const int ln = threadIdx.x & 63;
    const int wv = __builtin_amdgcn_readfirstlane(threadIdx.x >> 6);
    const int b0 = z * 8 + wv * 2;
    const int n  = y * 64 + ln;

    const float4*   __restrict__ wp  = Wt + ((size_t)(c * 8 + y) * 128) * 64 + ln;
    const uint32_t* __restrict__ pb0 = planes + ((b0 + 0) * Cc + c) * 16;
    const uint32_t* __restrict__ pb1 = planes + ((b0 + 1) * Cc + c) * 16;

    float acc0 = 0.f, acc1 = 0.f;
    float4 wa[8], wb[8];

    load_batch(wa, wp, 0);
    #pragma unroll 1
    for (int p = 0; p < 7; ++p) {
        load_batch(wb, wp, (2 * p + 1) * 8);
        compute_batch(wa, pb0[2 * p], pb1[2 * p], acc0, acc1);
        load_batch(wa, wp, (2 * p + 2) * 8);
        compute_batch(wb, pb0[2 * p + 1], pb1[2 * p + 1], acc0, acc1);
    }
    load_batch(wb, wp, 15 * 8);
    compute_batch(wa, pb0[14], pb1[14], acc0, acc1);
    compute_batch(wb, pb0[15], pb1[15], acc0, acc1);

    const float th = thr[c];
    {
        size_t off = ((size_t)(c * Bb + b0) * Nn) + n;
        float m = memb[off] + acc0;        // single add, like reference
        uint32_t wd = buf[off];
        if (th < m) { m -= th; wd |= (1u << t); }   // strict <
        memb[off] = m;
        buf[off] = wd;
    }
    {
        size_t off = ((size_t)(c * Bb + b0 + 1) * Nn) + n;
        float m = memb[off] + acc1;
        uint32_t wd = buf[off];
        if (th < m) { m -= th; wd |= (1u << t); }
        memb[off] = m;
        buf[off] = wd;
    }
}

// ---------------------------------------------------------------------------
// Fallback path (round-2, known-correct) if ws can't hold Wt.
// ---------------------------------------------------------------------------
__global__ void gather_kernel(const int* __restrict__ src_core,
                              const int* __restrict__ src_index,
                              const uint32_t* __restrict__ spk,
                              const uint32_t* __restrict__ buf,
                              float* __restrict__ sig, int t) {
    int idx = blockIdx.x * 256 + threadIdx.x;
    int b  = idx & 15;
    int ca = idx >> 4;
    int sc = src_core[ca];
    int si = src_index[ca];
    float v;
    if (sc < 0) {
        v = (float)((spk[b * INn + si] >> t) & 1u);
    } else {
        v = (t > 0) ? (float)((buf[(sc * Bb + b) * Nn + si] >> (t - 1)) & 1u)
                    : 0.0f;
    }
    sig[ca * 16 + b] = v;
}

__global__ __launch_bounds__(128) void cycle_kernel_fb(
        const float* __restrict__ W,
        const float* __restrict__ thr,
        const float* __restrict__ sig,
        uint32_t* __restrict__ buf,
        float* __restrict__ memb,
        int t) {
    const int c  = blockIdx.x;
    const int bh = __builtin_amdgcn_readfirstlane(threadIdx.x >> 6);
    const int n  = blockIdx.y * 64 + (threadIdx.x & 63);

    const float* __restrict__ wrow = W + (size_t)(c * Nn + n) * Aa;
    const float* __restrict__ sgc  = sig + c * Aa * 16 + bh * 8;

    float acc[8];
    #pragma unroll
    for (int j = 0; j < 8; ++j) acc[j] = 0.0f;

    for (int a0 = 0; a0 < Aa; a0 += 4) {
        float4 w4 = *(const float4*)(wrow + a0);
        #pragma unroll
        for (int k = 0; k < 4; ++k) {
            float w = (k == 0) ? w4.x : (k == 1) ? w4.y : (k == 2) ? w4.z : w4.w;
            const float* sa = sgc + (size_t)(a0 + k) * 16;
            #pragma unroll
            for (int j = 0; j < 8; ++j) acc[j] += w * sa[j];
        }
    }

    const float th = thr[c];
    #pragma unroll
    for (int j = 0; j < 8; ++j) {
        int b = bh * 8 + j;
        size_t off = (size_t)(c * Bb + b) * Nn + n;
        float m = memb[off] + acc[j];
        uint32_t wd = buf[off];
        if (th < m) { m -= th; wd |= (1u << t); }
        memb[off] = m;
        buf[off] = wd;
    }
}

// ---------------------------------------------------------------------------
// out[b, o] = popcount(buf[oc[o], b, oi[o]]).
// ---------------------------------------------------------------------------
__global__ void out_kernel(const uint32_t* __restrict__ buf,
                           const int* __restrict__ oc,
                           const int* __restrict__ oi,
                           float* __restrict__ out) {
    int idx = blockIdx.x * 256 + threadIdx.x;
    if (idx >= Bb * OUTo) return;
    int b = idx / OUTo;
    int o = idx - b * OUTo;
    uint32_t wd = buf[(oc[o] * Bb + b) * Nn + oi[o]];
    out[idx] = (float)__popc(wd);
}

extern "C" void kernel_launch(void* const* d_in, const int* in_sizes, int n_in,
                              void* d_out, int out_size, void* d_ws,
                              size_t ws_size, hipStream_t stream) {
    const float* x         = (const float*)d_in[0];
    const float* W         = (const float*)d_in[1];
    const float* thr       = (const float*)d_in[2];
    const int*   src_core  = (const int*)d_in[3];
    const int*   src_index = (const int*)d_in[4];
    const int*   osc       = (const int*)d_in[5];
    const int*   osi       = (const int*)d_in[6];
    float* out = (float*)d_out;

    // ws layout: spk | buf | memb | planes | sig(fallback) | Wt
    char* p = (char*)d_ws;
    uint32_t* spk    = (uint32_t*)p;  p += (size_t)Bb * INn * 4;
    uint32_t* buf    = (uint32_t*)p;  p += (size_t)Cc * Bb * Nn * 4;
    float*    memb   = (float*)p;     p += (size_t)Cc * Bb * Nn * 4;
    uint32_t* planes = (uint32_t*)p;  p += (size_t)Bb * Cc * 16 * 4;
    float*    sig    = (float*)p;     p += (size_t)Cc * Aa * Bb * 4;
    p = (char*)(((uintptr_t)p + 15) & ~(uintptr_t)15);
    float4*   Wt     = (float4*)p;    p += (size_t)Cc * Aa * Nn * 4;
    const bool use_t = ((size_t)(p - (char*)d_ws) <= ws_size);

    hipMemsetAsync(buf, 0, (size_t)Cc * Bb * Nn * 4 * 2, stream);

    spike_kernel<<<dim3((Bb * INn) / 256), 256, 0, stream>>>(x, spk);

    if (use_t) {
        transpose_kernel<<<dim3(Cc, 8, 8), 256, 0, stream>>>(W, Wt);
        for (int t = 0; t < Tt; ++t) {
            gatherbits_kernel<<<dim3((Bb * Cc * 16) / 256), 256, 0, stream>>>(
                src_core, src_index, spk, buf, planes, t);
            cycle_kernel<<<dim3(Cc, 8, 2), 256, 0, stream>>>(
                Wt, thr, planes, buf, memb, t);
        }
    } else {
        for (int t = 0; t < Tt; ++t) {
            gather_kernel<<<dim3((Cc * Aa * Bb) / 256), 256, 0, stream>>>(
                src_core, src_index, spk, buf, sig, t);
            cycle_kernel_fb<<<dim3(Cc, 8), 128, 0, stream>>>(
                W, thr, sig, buf, memb, t);
        }
    }

    out_kernel<<<dim3((Bb * OUTo + 255) / 256), 256, 0, stream>>>(
        buf, osc, osi, out);
}

// Round 5
// 1519.106 us; speedup vs baseline: 1.1929x; 1.0484x over previous
//
#include <hip/hip_runtime.h>
#include <stdint.h>

#define Bb   16
#define INn  8192
#define Cc   64
#define Aa   512
#define Nn   512
#define OUTo 1024
#define Tt   32

// ---------------------------------------------------------------------------
// Spike schedule per (b, i) as a 32-bit mask (bit t = spike at cycle t).
// ---------------------------------------------------------------------------
__global__ void spike_kernel(const float* __restrict__ x,
                             uint32_t* __restrict__ spk) {
    int idx = blockIdx.x * 256 + threadIdx.x;
    if (idx >= Bb * INn) return;
    float xv = x[idx];
    float nf = rintf(xv * 32.0f);
    int nspk = (int)nf;
    uint32_t m;
    if (nspk >= 32) {
        m = 0xFFFFFFFFu;
    } else if (nspk <= 0) {
        m = 0u;
    } else {
        float spacing = 32.0f / nf;
        m = 0u;
        #pragma unroll
        for (int t = 0; t < 32; ++t) {
            float ct = (float)t;
            bool fire = (floorf(ct / spacing) < nf) &&
                        (floorf(fmodf(ct, spacing)) == 0.0f);
            if (fire) m |= (1u << t);
        }
    }
    spk[idx] = m;
}

// ---------------------------------------------------------------------------
// One-time W transpose into block-contiguous a-major layout:
//   Wt[((c*8 + nt)*128 + ab)*64 + ln] = float4{ W[c][nt*64+ln][4ab .. 4ab+3] }
// Cycle block (c,nt) streams a CONTIGUOUS 128 KB region.
// ---------------------------------------------------------------------------
__global__ __launch_bounds__(256) void transpose_kernel(
        const float* __restrict__ W, float4* __restrict__ Wt) {
    __shared__ float lds[64 * 65];
    const int c  = blockIdx.x;
    const int nt = blockIdx.y;
    const int at = blockIdx.z;
    const int tx = threadIdx.x & 63;
    const int ty = threadIdx.x >> 6;

    const float* src = W + (size_t)c * Nn * Aa;
    for (int r = ty; r < 64; r += 4) {
        lds[r * 65 + tx] = src[(size_t)(nt * 64 + r) * Aa + at * 64 + tx];
    }
    __syncthreads();
    #pragma unroll
    for (int i = 0; i < 4; ++i) {
        int ab = i * 4 + ty;
        float4 w4;
        w4.x = lds[tx * 65 + ab * 4 + 0];
        w4.y = lds[tx * 65 + ab * 4 + 1];
        w4.z = lds[tx * 65 + ab * 4 + 2];
        w4.w = lds[tx * 65 + ab * 4 + 3];
        size_t dst = ((size_t)(c * 8 + nt) * 128 + (at * 16 + ab)) * 64 + tx;
        Wt[dst] = w4;
    }
}

// ---------------------------------------------------------------------------
// Per-cycle signal gather: sig[(c*512+a)*16 + b] = 0.0f / 1.0f.
// ---------------------------------------------------------------------------
__global__ void gather_kernel(const int* __restrict__ src_core,
                              const int* __restrict__ src_index,
                              const uint32_t* __restrict__ spk,
                              const uint32_t* __restrict__ buf,
                              float* __restrict__ sig, int t) {
    int idx = blockIdx.x * 256 + threadIdx.x;
    int b  = idx & 15;
    int ca = idx >> 4;
    int sc = src_core[ca];
    int si = src_index[ca];
    float v;
    if (sc < 0) {
        v = (float)((spk[b * INn + si] >> t) & 1u);
    } else {
        v = (t > 0) ? (float)((buf[(sc * Bb + b) * Nn + si] >> (t - 1)) & 1u)
                    : 0.0f;
    }
    sig[ca * 16 + b] = v;
}

// ---------------------------------------------------------------------------
// Cycle kernel: LDS-staged W stream via global_load_lds, counted vmcnt,
// double-buffered 8 KB chunks. Grid (64 c, 8 nt) x 256 threads (4 waves).
// Wave wv owns b-quad sb=4*wv; lane ln owns n = nt*64+ln. Each chunk =
// 8 a-groups (32 a). All 4 waves read the same LDS W stream (ds_read_b128,
// lane-consecutive, conflict-free). sig is wave-uniform -> s_load_dwordx4.
// Accumulation strictly ascending in a per (c,b,n) accumulator ->
// bit-identical to the validated rounds.
// Linear block id = c + 64*nt -> id%8 = c%8: all 8 blocks of a core land on
// one XCD, so the core's 1 MB W slice stays hot in that XCD's L2 across
// cycles.
// ---------------------------------------------------------------------------
typedef const __attribute__((address_space(1))) uint32_t* gas_u32p;
typedef __attribute__((address_space(3))) uint32_t* las_u32p;

__global__ __launch_bounds__(256) void cycle_kernel(
        const float4* __restrict__ Wt,
        const float* __restrict__ thr,
        const float* __restrict__ sig,
        uint32_t* __restrict__ buf,
        float* __restrict__ memb,
        int t) {
    __shared__ float4 stage[2][512];           // 2 x 8 KB

    const int c   = blockIdx.x;
    const int nt  = blockIdx.y;
    const int tid = threadIdx.x;
    const int ln  = tid & 63;
    const int wv  = __builtin_amdgcn_readfirstlane(tid >> 6);
    const int sb  = wv * 4;
    const int n   = nt * 64 + ln;

    const float4* __restrict__ gW  = Wt + (size_t)(c * 8 + nt) * 128 * 64;
    const float*  __restrict__ sgp = sig + (size_t)c * Aa * Bb + sb;

    float acc0 = 0.f, acc1 = 0.f, acc2 = 0.f, acc3 = 0.f;

    // stage chunk 0 (2 x 4 KB async direct-to-LDS)
    {
        #pragma unroll
        for (int m = 0; m < 2; ++m) {
            const float4* g = gW + m * 256 + tid;
            uint32_t* l = (uint32_t*)&stage[0][m * 256 + wv * 64];
            __builtin_amdgcn_global_load_lds((gas_u32p)(const void*)g,
                                             (las_u32p)(void*)l, 16, 0, 0);
        }
    }

    #pragma unroll 1
    for (int k = 0; k < 16; ++k) {
        if (k < 15) {
            // prefetch chunk k+1 into the other buffer
            #pragma unroll
            for (int m = 0; m < 2; ++m) {
                const float4* g = gW + (k + 1) * 512 + m * 256 + tid;
                uint32_t* l = (uint32_t*)&stage[(k + 1) & 1][m * 256 + wv * 64];
                __builtin_amdgcn_global_load_lds((gas_u32p)(const void*)g,
                                                 (las_u32p)(void*)l, 16, 0, 0);
            }
            asm volatile("s_waitcnt vmcnt(2)" ::: "memory");  // chunk k landed
        } else {
            asm volatile("s_waitcnt vmcnt(0)" ::: "memory");
        }
        __builtin_amdgcn_s_barrier();          // all waves' stage data visible

        const float4* bufp = &stage[k & 1][0];
        #pragma unroll
        for (int j = 0; j < 8; ++j) {
            float4 w4 = bufp[j * 64 + ln];
            const int a0 = k * 32 + j * 4;
            float4 s0 = *(const float4*)(sgp + (size_t)(a0 + 0) * 16);
            float4 s1 = *(const float4*)(sgp + (size_t)(a0 + 1) * 16);
            float4 s2 = *(const float4*)(sgp + (size_t)(a0 + 2) * 16);
            float4 s3 = *(const float4*)(sgp + (size_t)(a0 + 3) * 16);
            acc0 += w4.x * s0.x; acc1 += w4.x * s0.y;
            acc2 += w4.x * s0.z; acc3 += w4.x * s0.w;
            acc0 += w4.y * s1.x; acc1 += w4.y * s1.y;
            acc2 += w4.y * s1.z; acc3 += w4.y * s1.w;
            acc0 += w4.z * s2.x; acc1 += w4.z * s2.y;
            acc2 += w4.z * s2.z; acc3 += w4.z * s2.w;
            acc0 += w4.w * s3.x; acc1 += w4.w * s3.y;
            acc2 += w4.w * s3.z; acc3 += w4.w * s3.w;
        }
        __builtin_amdgcn_s_barrier();          // done reading before restage
    }

    const float th = thr[c];
    float accs[4] = {acc0, acc1, acc2, acc3};
    #pragma unroll
    for (int j = 0; j < 4; ++j) {
        size_t off = ((size_t)c * Bb + (sb + j)) * Nn + n;
        float m = memb[off] + accs[j];         // single add, like reference
        uint32_t wd = buf[off];
        if (th < m) { m -= th; wd |= (1u << t); }   // strict <
        memb[off] = m;
        buf[off] = wd;
    }
}

// ---------------------------------------------------------------------------
// Fallback cycle kernel (round-2, known-correct) if ws can't hold Wt.
// ---------------------------------------------------------------------------
__global__ __launch_bounds__(128) void cycle_kernel_fb(
        const float* __restrict__ W,
        const float* __restrict__ thr,
        const float* __restrict__ sig,
        uint32_t* __restrict__ buf,
        float* __restrict__ memb,
        int t) {
    const int c  = blockIdx.x;
    const int bh = __builtin_amdgcn_readfirstlane(threadIdx.x >> 6);
    const int n  = blockIdx.y * 64 + (threadIdx.x & 63);

    const float* __restrict__ wrow = W + (size_t)(c * Nn + n) * Aa;
    const float* __restrict__ sgc  = sig + c * Aa * 16 + bh * 8;

    float acc[8];
    #pragma unroll
    for (int j = 0; j < 8; ++j) acc[j] = 0.0f;

    for (int a0 = 0; a0 < Aa; a0 += 4) {
        float4 w4 = *(const float4*)(wrow + a0);
        #pragma unroll
        for (int k = 0; k < 4; ++k) {
            float w = (k == 0) ? w4.x : (k == 1) ? w4.y : (k == 2) ? w4.z : w4.w;
            const float* sa = sgc + (size_t)(a0 + k) * 16;
            #pragma unroll
            for (int j = 0; j < 8; ++j) acc[j] += w * sa[j];
        }
    }

    const float th = thr[c];
    #pragma unroll
    for (int j = 0; j < 8; ++j) {
        int b = bh * 8 + j;
        size_t off = (size_t)(c * Bb + b) * Nn + n;
        float m = memb[off] + acc[j];
        uint32_t wd = buf[off];
        if (th < m) { m -= th; wd |= (1u << t); }
        memb[off] = m;
        buf[off] = wd;
    }
}

// ---------------------------------------------------------------------------
// out[b, o] = popcount(buf[oc[o], b, oi[o]]).
// ---------------------------------------------------------------------------
__global__ void out_kernel(const uint32_t* __restrict__ buf,
                           const int* __restrict__ oc,
                           const int* __restrict__ oi,
                           float* __restrict__ out) {
    int idx = blockIdx.x * 256 + threadIdx.x;
    if (idx >= Bb * OUTo) return;
    int b = idx / OUTo;
    int o = idx - b * OUTo;
    uint32_t wd = buf[(oc[o] * Bb + b) * Nn + oi[o]];
    out[idx] = (float)__popc(wd);
}

extern "C" void kernel_launch(void* const* d_in, const int* in_sizes, int n_in,
                              void* d_out, int out_size, void* d_ws,
                              size_t ws_size, hipStream_t stream) {
    const float* x         = (const float*)d_in[0];
    const float* W         = (const float*)d_in[1];
    const float* thr       = (const float*)d_in[2];
    const int*   src_core  = (const int*)d_in[3];
    const int*   src_index = (const int*)d_in[4];
    const int*   osc       = (const int*)d_in[5];
    const int*   osi       = (const int*)d_in[6];
    float* out = (float*)d_out;

    // ws layout: spk | buf | memb | sig | Wt
    char* p = (char*)d_ws;
    uint32_t* spk  = (uint32_t*)p;   p += (size_t)Bb * INn * 4;
    uint32_t* buf  = (uint32_t*)p;   p += (size_t)Cc * Bb * Nn * 4;
    float*    memb = (float*)p;      p += (size_t)Cc * Bb * Nn * 4;
    float*    sig  = (float*)p;      p += (size_t)Cc * Aa * Bb * 4;
    p = (char*)(((uintptr_t)p + 255) & ~(uintptr_t)255);
    float4*   Wt   = (float4*)p;     p += (size_t)Cc * Aa * Nn * 4;
    const bool use_t = ((size_t)(p - (char*)d_ws) <= ws_size);

    hipMemsetAsync(buf, 0, (size_t)Cc * Bb * Nn * 4 * 2, stream);

    spike_kernel<<<dim3((Bb * INn) / 256), 256, 0, stream>>>(x, spk);

    if (use_t) {
        transpose_kernel<<<dim3(Cc, 8, 8), 256, 0, stream>>>(W, Wt);
        for (int t = 0; t < Tt; ++t) {
            gather_kernel<<<dim3((Cc * Aa * Bb) / 256), 256, 0, stream>>>(
                src_core, src_index, spk, buf, sig, t);
            cycle_kernel<<<dim3(Cc, 8), 256, 0, stream>>>(
                Wt, thr, sig, buf, memb, t);
        }
    } else {
        for (int t = 0; t < Tt; ++t) {
            gather_kernel<<<dim3((Cc * Aa * Bb) / 256), 256, 0, stream>>>(
                src_core, src_index, spk, buf, sig, t);
            cycle_kernel_fb<<<dim3(Cc, 8), 128, 0, stream>>>(
                W, thr, sig, buf, memb, t);
        }
    }

    out_kernel<<<dim3((Bb * OUTo + 255) / 256), 256, 0, stream>>>(
        buf, osc, osi, out);
}